// Round 1
// 894.484 us; speedup vs baseline: 1.1078x; 1.1078x over previous
//
#include <hip/hip_runtime.h>
#include <math.h>

#define BSZ   16
#define NDIM  128
#define KNEG  65536
#define KP1   65537
#define NDATA 1000000
#define NROWS (BSZ * KP1)        // 1,048,592 (divisible by 8)
#define NPART 1024               // partial-sum slots (power of 2)
#define INV_T (1.0f / 0.07f)

#define GBLK  (NROWS / 8)        // 131,074 blocks; 8 rows each, no tail
#define N4MEM (NDATA * (NDIM / 4))   // 32,000,000 float4 in memory
// copy coverage: GBLK*256 = 33,554,944 threads >= N4MEM -> <=1 float4/thread
#define SCALE_BLK 2048
#define N4LX  (2 * NROWS / 4)    // 524,296 float4 of lx||lz

// ---------------------------------------------------------------------------
// Kernel 1 (fused): every block does
//   (a) one 4 KB streaming slice of the mem -> out_mem copy (load issued
//       first, store retired last, so it overlaps the random gather), and
//   (b) 8 gathered rows: dual dot products, exp, raw write + partial sum.
// The random 512-B gather reads are latency-bound and cannot saturate HBM
// alone; interleaving the streaming copy in the same wave pool fills the
// idle bandwidth instead of paying for it twice in serialized kernels.
// ---------------------------------------------------------------------------
__global__ __launch_bounds__(256) void fused_main_kernel(
    const float* __restrict__ mem, const float* __restrict__ x,
    const float* __restrict__ z, const int* __restrict__ y,
    const int* __restrict__ idx, float* __restrict__ out_lx,
    float* __restrict__ out_lz, float* __restrict__ out_mem,
    double* __restrict__ partials)
{
    __shared__ float s_lx[8];
    const int tid = threadIdx.x;
    const int bid = blockIdx.x;

    // ---- streaming copy slice: issue the independent load early ----
    const size_t ci = (size_t)bid * 256 + tid;
    const bool do_copy = (ci < (size_t)N4MEM);
    float4 cv;
    if (do_copy) cv = ((const float4*)mem)[ci];

    // ---- gather + dual dot: 32 lanes per row (32 x float4 = 512 B) ----
    const int group = tid >> 5;        // 0..7
    const int lane  = tid & 31;        // 0..31
    const int r     = bid * 8 + group; // global row id, < NROWS

    const int b   = r / KP1;
    const int k   = r - b * KP1;
    const int row = (k == 0) ? y[b] : idx[b * KNEG + (k - 1)];

    float4 mv = ((const float4*)(mem + (size_t)row * NDIM))[lane];
    float4 xv = ((const float4*)(x + b * NDIM))[lane];
    float4 zv = ((const float4*)(z + b * NDIM))[lane];

    float px = mv.x * xv.x + mv.y * xv.y + mv.z * xv.z + mv.w * xv.w;
    float pz = mv.x * zv.x + mv.y * zv.y + mv.z * zv.z + mv.w * zv.w;

    // reduce across the 32-lane group (masks <=16 stay inside the group)
    #pragma unroll
    for (int m = 16; m >= 1; m >>= 1) {
        px += __shfl_xor(px, m, 64);
        pz += __shfl_xor(pz, m, 64);
    }

    if (lane == 0) {
        float lxv = expf(px * INV_T);
        float lzv = expf(pz * INV_T);
        out_lx[r] = lxv;
        out_lz[r] = lzv;
        s_lx[group] = lxv;
    }

    // ---- retire the copy store (cv has been sitting in 4 VGPRs) ----
    if (do_copy) ((float4*)out_mem)[ci] = cv;

    __syncthreads();
    if (tid == 0) {
        double s = 0.0;
        #pragma unroll
        for (int g = 0; g < 8; ++g) s += (double)s_lx[g];
        atomicAdd(&partials[bid & (NPART - 1)], s);
    }
}

// ---------------------------------------------------------------------------
// Kernel 2 (fused finish):
//   blocks [0, SCALE_BLK):   each block independently reduces the 1024
//       partials (8 KB, L2-hot, identical order in every block -> bitwise-
//       identical z0) and scales its slice of lx/lz in place. No separate
//       finalize kernel, no extra dependency in the stream.
//   blocks [SCALE_BLK, +16): parallel EMA update of the 16 positive rows
//       (one block per b; "last duplicate wins" handled by a lookahead
//       check instead of a serial loop). Runs after the copy by kernel
//       ordering, so the copy needs no skip logic.
// ---------------------------------------------------------------------------
__global__ __launch_bounds__(256) void finish_kernel(
    const float* __restrict__ mem, const float* __restrict__ x,
    const int* __restrict__ y, const double* __restrict__ partials,
    float4* __restrict__ lxlz, float* __restrict__ out_mem)
{
    const int tid = threadIdx.x;
    const int bid = blockIdx.x;

    if (bid < SCALE_BLK) {
        __shared__ double sh[256];
        double s = 0.0;
        #pragma unroll
        for (int i = 0; i < NPART / 256; ++i) s += partials[tid + i * 256];
        sh[tid] = s;
        __syncthreads();
        #pragma unroll
        for (int off = 128; off >= 1; off >>= 1) {
            if (tid < off) sh[tid] += sh[tid + off];
            __syncthreads();
        }
        const double z0 = (sh[0] / (double)NROWS) * (double)NDATA;
        const float  sc = (float)(1.0 / z0);
        for (int i = bid * 256 + tid; i < N4LX; i += SCALE_BLK * 256) {
            float4 v = lxlz[i];
            v.x *= sc; v.y *= sc; v.z *= sc; v.w *= sc;
            lxlz[i] = v;
        }
    } else {
        const int b   = bid - SCALE_BLK;   // 0..15
        const int row = y[b];
        bool last = true;
        for (int j = b + 1; j < BSZ; ++j)
            if (y[j] == row) last = false; // a later b writes this row
        if (last && tid < 64) {
            float2 m  = ((const float2*)(mem + (size_t)row * NDIM))[tid];
            float2 xv = ((const float2*)(x + (size_t)b * NDIM))[tid];
            float w0 = 0.5f * m.x + 0.5f * xv.x;
            float w1 = 0.5f * m.y + 0.5f * xv.y;
            float ss = w0 * w0 + w1 * w1;
            #pragma unroll
            for (int mk = 32; mk >= 1; mk >>= 1) ss += __shfl_xor(ss, mk, 64);
            const float inv = 1.0f / sqrtf(ss);
            ((float2*)(out_mem + (size_t)row * NDIM))[tid] =
                make_float2(w0 * inv, w1 * inv);
        }
    }
}

// ---------------------------------------------------------------------------
extern "C" void kernel_launch(void* const* d_in, const int* in_sizes, int n_in,
                              void* d_out, int out_size, void* d_ws, size_t ws_size,
                              hipStream_t stream)
{
    const float* x   = (const float*)d_in[0];
    const float* z   = (const float*)d_in[1];
    const float* mem = (const float*)d_in[2];
    const int*   y   = (const int*)d_in[3];
    const int*   idx = (const int*)d_in[4];

    float* out_lx  = (float*)d_out;
    float* out_lz  = out_lx + NROWS;
    float* out_mem = out_lz + NROWS;
    double* ws     = (double*)d_ws;    // [0..NPART-1] partial sums

    // ws is poisoned 0xAA before every launch -> zero the partials.
    hipMemsetAsync(d_ws, 0, NPART * sizeof(double), stream);

    fused_main_kernel<<<GBLK, 256, 0, stream>>>(
        mem, x, z, y, idx, out_lx, out_lz, out_mem, ws);

    finish_kernel<<<SCALE_BLK + BSZ, 256, 0, stream>>>(
        mem, x, y, ws, (float4*)d_out, out_mem);
}